// Round 3
// baseline (368.178 us; speedup 1.0000x reference)
//
#include <hip/hip_runtime.h>

// NestedMoEModel: B=32768, D=256, H=256, G=8, E=8.
// softmax row-sum == 1 => gate branch drops; sum_e is linear =>
// single GEMM  out[32768,2048] = x @ (sum_e W_exp)^T + sum_e b_exp.
// R5: B (Ws, 1 MB, L2-resident) bypasses LDS entirely -> registers, prefetched
// one K-tile ahead. A keeps the glds path, double-buffered at 2x16 KB (same
// 32 KB as R0 => 3 blocks/CU restored). Counted s_waitcnt vmcnt(12) so next
// tile's 12 VMEM ops stay in flight across the barrier. Swapped-operand MFMA
// + float4 C stores (R2-verified numerics).

typedef unsigned short u16;
typedef __bf16 bf16x8 __attribute__((ext_vector_type(8)));
typedef float f32x4 __attribute__((ext_vector_type(4)));

#define MB 32768   // batch (GEMM M)
#define NN 2048    // G*H   (GEMM N)
#define KK 256     // D     (GEMM K)
#define BK 64

__device__ __forceinline__ u16 f2bf(float f) {
    unsigned u = __builtin_bit_cast(unsigned, f);
    u += 0x7FFFu + ((u >> 16) & 1u);
    return (u16)(u >> 16);
}

__device__ __forceinline__ void gld16(const void* g, void* l) {
    // async global->LDS, 16B/lane; LDS dest must be wave-uniform base + lane*16
    __builtin_amdgcn_global_load_lds((const __attribute__((address_space(1))) void*)g,
                                     (__attribute__((address_space(3))) void*)l,
                                     16, 0, 0);
}

// ---------------- prep: Wsum/bsum fold + x fp32->bf16 (R0-proven) ----------------
__global__ __launch_bounds__(256) void prep_kernel(
    const float* __restrict__ x, const float* __restrict__ Wexp,
    const float* __restrict__ bexp, u16* __restrict__ xb,
    u16* __restrict__ Ws, float* __restrict__ bs)
{
    const int blk = blockIdx.x;
    const int t = threadIdx.x;
    if (blk < 512) {
        const int tid = blk * 256 + t;        // 0..131071
        const int n = tid >> 6;               // 0..2047
        const int i = (tid & 63) << 2;        // 0..252
        const int g = n >> 8, h = n & 255;
        const float* base = Wexp + ((size_t)(g * 8) * 256 + h) * 256 + i;
        float s0 = 0.f, s1 = 0.f, s2 = 0.f, s3 = 0.f;
#pragma unroll
        for (int e = 0; e < 8; ++e) {
            const float4 v = *(const float4*)(base + (size_t)e * 65536);
            s0 += v.x; s1 += v.y; s2 += v.z; s3 += v.w;
        }
        ushort4 o;
        o.x = f2bf(s0); o.y = f2bf(s1); o.z = f2bf(s2); o.w = f2bf(s3);
        *(ushort4*)(Ws + (size_t)n * KK + i) = o;
        if ((tid & 63) == 0) {
            float sb = 0.f;
#pragma unroll
            for (int e = 0; e < 8; ++e) sb += bexp[(g * 8 + e) * 256 + h];
            bs[n] = sb;
        }
    } else {
        int idx = (blk - 512) * 256 + t;      // 0..524287
        const float4* xv = (const float4*)x;
#pragma unroll
        for (int it = 0; it < 4; ++it) {
            const int j = idx + it * 524288;
            const float4 v = xv[j];
            ushort4 o;
            o.x = f2bf(v.x); o.y = f2bf(v.y); o.z = f2bf(v.z); o.w = f2bf(v.w);
            *(ushort4*)(xb + (size_t)j * 4) = o;
        }
    }
}

// ---------------- GEMM: C = A * Bt^T + bias ----------------
// 128x128 tile, BK=64, 4 waves (2x2 of 64x64), 16x16x32 bf16 MFMA.
// A: glds -> LDS, XOR-swizzled rows (chunk^(row&7) applied on the GLOBAL
//    source address), double-buffered 2x16 KB.
// B: straight from L2 into registers (bf16x8 fragments), double-buffered.
// Per iter: 4 glds + 8 B-loads issued for tile it+1, s_waitcnt vmcnt(12)
// (tile it's 12 ops landed, it+1's stay in flight), s_barrier, compute.
__global__ __launch_bounds__(256, 3) void gemm_kernel(
    const u16* __restrict__ A, const u16* __restrict__ Bt,
    const float* __restrict__ bias, float* __restrict__ C)
{
    __shared__ __align__(16) u16 sA[2][128 * BK];

    const int t = threadIdx.x;
    const int n0 = blockIdx.x * 128;   // x fastest: 16 consecutive blocks share A-tile
    const int m0 = blockIdx.y * 128;

    const int lane = t & 63;
    const int w = t >> 6;
    const int wm = (w & 1) << 6;
    const int wn = (w >> 1) << 6;
    const int lr = lane & 15;
    const int quad = lane >> 4;

    f32x4 acc[4][4] = {};

    // A staging decomposition: slot = r*256+t -> row = slot>>3, chunk = slot&7
    const int srow = t >> 3;
    const int scs  = t & 7;

    // B fragment base: row = n0+wn+ni*16+lr, col-chunk = (kk*4+quad)*8 (+k0)
    const u16* bbase = Bt + (size_t)(n0 + wn + lr) * KK + quad * 8;

#define STAGEA(P, K0)                                                   \
    {                                                                   \
        _Pragma("unroll")                                               \
        for (int r = 0; r < 4; ++r) {                                   \
            const int row = srow + r * 32;                              \
            const int gc  = ((scs ^ (row & 7)) << 3);                   \
            gld16(A + (size_t)(m0 + row) * KK + (K0) + gc,              \
                  sA[P] + (size_t)(r * 256 + t) * 8);                   \
        }                                                               \
    }

#define LOADB(DST, K0)                                                  \
    {                                                                   \
        _Pragma("unroll")                                               \
        for (int kk = 0; kk < 2; ++kk)                                  \
            _Pragma("unroll")                                           \
            for (int ni = 0; ni < 4; ++ni)                              \
                DST[kk * 4 + ni] = *(const bf16x8*)(                    \
                    bbase + (size_t)ni * 16 * KK + (K0) + kk * 32);     \
    }

    bf16x8 b0[8], b1[8];

    // prologue: tile 0 in flight (4 glds + 8 B-loads)
    STAGEA(0, 0);
    LOADB(b0, 0);

#define BODY(IT, P, BC, BN)                                             \
    {                                                                   \
        if ((IT) < 3) {                                                 \
            STAGEA(P ^ 1, ((IT) + 1) * BK);                             \
            LOADB(BN, ((IT) + 1) * BK);                                 \
            asm volatile("s_waitcnt vmcnt(12)" ::: "memory");           \
        } else {                                                        \
            asm volatile("s_waitcnt vmcnt(0)" ::: "memory");            \
        }                                                               \
        __builtin_amdgcn_s_barrier();                                   \
        _Pragma("unroll")                                               \
        for (int kk = 0; kk < 2; ++kk) {                                \
            bf16x8 af[4];                                               \
            _Pragma("unroll")                                           \
            for (int mi = 0; mi < 4; ++mi) {                            \
                const int rr = wm + mi * 16 + lr;                       \
                const int c  = (kk * 4 + quad) ^ (rr & 7);              \
                af[mi] = *(const bf16x8*)(sA[P] + rr * BK + (c << 3));  \
            }                                                           \
            /* SWAPPED: acc[mi][ni][r] = C[wm+mi*16+lr][wn+ni*16+quad*4+r] */ \
            _Pragma("unroll")                                           \
            for (int mi = 0; mi < 4; ++mi)                              \
                _Pragma("unroll")                                       \
                for (int ni = 0; ni < 4; ++ni)                          \
                    acc[mi][ni] = __builtin_amdgcn_mfma_f32_16x16x32_bf16( \
                        BC[kk * 4 + ni], af[mi], acc[mi][ni], 0, 0, 0); \
        }                                                               \
        if ((IT) < 3) __builtin_amdgcn_s_barrier();                     \
    }

    BODY(0, 0, b0, b1);
    BODY(1, 1, b1, b0);
    BODY(2, 0, b0, b1);
    BODY(3, 1, b1, b0);

#undef BODY
#undef LOADB
#undef STAGEA

    // epilogue: float4 stores along n (reg index r runs along n after swap)
#pragma unroll
    for (int mi = 0; mi < 4; ++mi) {
        const int row = m0 + wm + mi * 16 + lr;
        float* Cp = C + (size_t)row * NN;
#pragma unroll
        for (int ni = 0; ni < 4; ++ni) {
            const int col = n0 + wn + ni * 16 + quad * 4;
            const f32x4 bv = *(const f32x4*)(bias + col);
            f32x4 v = acc[mi][ni] + bv;
            *(f32x4*)(Cp + col) = v;
        }
    }
}

extern "C" void kernel_launch(void* const* d_in, const int* in_sizes, int n_in,
                              void* d_out, int out_size, void* d_ws, size_t ws_size,
                              hipStream_t stream) {
    const float* x    = (const float*)d_in[0];
    // d_in[1] = W_gate, d_in[2] = b_gate: unused (softmax row-sum == 1)
    const float* Wexp = (const float*)d_in[3];
    const float* bexp = (const float*)d_in[4];
    float* out = (float*)d_out;

    u16*   xb = (u16*)d_ws;                                         // 16 MB
    u16*   Ws = (u16*)((char*)d_ws + (size_t)16777216);             // 1 MB
    float* bs = (float*)((char*)d_ws + (size_t)16777216 + 1048576); // 8 KB

    prep_kernel<<<2560, 256, 0, stream>>>(x, Wexp, bexp, xb, Ws, bs);
    dim3 grid(NN / 128, MB / 128);  // (16, 256) — n fastest
    gemm_kernel<<<grid, 256, 0, stream>>>(xb, Ws, bs, out);
}

// Round 4
// 356.996 us; speedup vs baseline: 1.0313x; 1.0313x over previous
//
#include <hip/hip_runtime.h>

// NestedMoEModel: B=32768, D=256, H=256, G=8, E=8.
// softmax row-sum == 1 => gate branch drops; sum_e is linear =>
// single GEMM  out[32768,2048] = x @ (sum_e W_exp)^T + sum_e b_exp.
// R6: R0's proven GEMM skeleton (single-buffered glds, __syncthreads, 3
// blocks/CU) but A is staged as RAW FP32 via glds (32KB tile) and converted
// to bf16 at fragment-read time (v_cvt_pk_bf16_f32). Kills the 2048-block
// x->bf16 prep pass + its 32MB HBM round-trip. B path byte-identical to R0.
// A-LDS swizzle: 16B unit ^ (row&15) on the GLOBAL source address
// (involution; fragment reads land at the 8-lane/bank wave64-b128 floor).

typedef unsigned short u16;
typedef __bf16 bf16x8 __attribute__((ext_vector_type(8)));
typedef float f32x4 __attribute__((ext_vector_type(4)));

#define MB 32768   // batch (GEMM M)
#define NN 2048    // G*H   (GEMM N)
#define KK 256     // D     (GEMM K)
#define BK 64

__device__ __forceinline__ u16 f2bf(float f) {
    unsigned u = __builtin_bit_cast(unsigned, f);
    u += 0x7FFFu + ((u >> 16) & 1u);
    return (u16)(u >> 16);
}

// packed fp32x2 -> bf16x2 (RNE) — same rounding as f2bf
__device__ __forceinline__ unsigned cvtpk(float lo, float hi) {
    unsigned r;
    asm("v_cvt_pk_bf16_f32 %0, %1, %2" : "=v"(r) : "v"(lo), "v"(hi));
    return r;
}

__device__ __forceinline__ void gld16(const void* g, void* l) {
    // async global->LDS, 16B/lane; LDS dest must be wave-uniform base + lane*16
    __builtin_amdgcn_global_load_lds((const __attribute__((address_space(1))) void*)g,
                                     (__attribute__((address_space(3))) void*)l,
                                     16, 0, 0);
}

// ---------------- prep: Wsum (bf16) + bsum fold only ----------------
__global__ __launch_bounds__(256) void prep_kernel(
    const float* __restrict__ Wexp, const float* __restrict__ bexp,
    u16* __restrict__ Ws, float* __restrict__ bs)
{
    const int tid = blockIdx.x * 256 + threadIdx.x;  // 0..131071
    const int n = tid >> 6;                          // 0..2047
    const int i = (tid & 63) << 2;                   // 0..252
    const int g = n >> 8, h = n & 255;
    const float* base = Wexp + ((size_t)(g * 8) * 256 + h) * 256 + i;
    float s0 = 0.f, s1 = 0.f, s2 = 0.f, s3 = 0.f;
#pragma unroll
    for (int e = 0; e < 8; ++e) {
        const float4 v = *(const float4*)(base + (size_t)e * 65536);
        s0 += v.x; s1 += v.y; s2 += v.z; s3 += v.w;
    }
    ushort4 o;
    o.x = f2bf(s0); o.y = f2bf(s1); o.z = f2bf(s2); o.w = f2bf(s3);
    *(ushort4*)(Ws + (size_t)n * KK + i) = o;
    if ((tid & 63) == 0) {
        float sb = 0.f;
#pragma unroll
        for (int e = 0; e < 8; ++e) sb += bexp[(g * 8 + e) * 256 + h];
        bs[n] = sb;
    }
}

// ---------------- GEMM: C = x * Ws^T + bias ----------------
// 128x128 tile, BK=64, 4 waves (2x2 of 64x64), 16x16x32 bf16 MFMA.
// A: fp32 in LDS (128 x 64 f32 = 32KB), 16B-unit swizzle q^(row&15) applied
//    on global source; fragment read = 2x ds_read_b128 + 4x cvt_pk.
// B: bf16 in LDS (16KB), chunk^(row&7) swizzle — byte-identical to R0.
__global__ __launch_bounds__(256, 3) void gemm_kernel(
    const float* __restrict__ X, const u16* __restrict__ Bt,
    const float* __restrict__ bias, float* __restrict__ C)
{
    __shared__ __align__(16) float sA[128 * BK];  // 32 KB
    __shared__ __align__(16) u16   sB[128 * BK];  // 16 KB

    const int t = threadIdx.x;
    const int n0 = blockIdx.x * 128;   // x fastest: 16 consecutive blocks share A-panel
    const int m0 = blockIdx.y * 128;

    const int lane = t & 63;
    const int w = t >> 6;
    const int wm = (w & 1) << 6;
    const int wn = (w >> 1) << 6;
    const int lr = lane & 15;
    const int quad = lane >> 4;

    f32x4 acc[4][4] = {};

    // A staging: slot = r*256+t -> row = slot>>4 (16 x 16B units/row), unit = slot&15
    const int arow = t >> 4;
    const int aq   = t & 15;
    // B staging: slot = r*256+t -> row = slot>>3 (8 x 8-elem chunks/row), chunk = slot&7
    const int brow = t >> 3;
    const int bcs  = t & 7;

    for (int k0 = 0; k0 < KK; k0 += BK) {
        // B: 4 glds rounds (bf16, R0 path)
#pragma unroll
        for (int r = 0; r < 4; ++r) {
            const int row = brow + r * 32;
            const int gc  = ((bcs ^ (row & 7)) << 3);
            gld16(Bt + (size_t)(n0 + row) * KK + k0 + gc, sB + (size_t)(r * 256 + t) * 8);
        }
        // A: 8 glds rounds (fp32, swizzled 16B units)
#pragma unroll
        for (int r = 0; r < 8; ++r) {
            const int row = arow + r * 16;
            const int q   = aq ^ (row & 15);
            gld16(X + (size_t)(m0 + row) * KK + k0 + (q << 2), sA + (size_t)(r * 256 + t) * 4);
        }
        __syncthreads();

#pragma unroll
        for (int kk = 0; kk < 2; ++kk) {
            bf16x8 af[4], bfr[4];
#pragma unroll
            for (int mi = 0; mi < 4; ++mi) {
                const int rr = wm + mi * 16 + lr;
                const int m  = rr & 15;
                const int q0 = kk * 8 + quad * 2;          // logical 16B unit (even)
                const f32x4 lo = *(const f32x4*)(sA + rr * BK + ((q0 ^ m) << 2));
                const f32x4 hi = *(const f32x4*)(sA + rr * BK + (((q0 ^ m) ^ 1) << 2));
                union { bf16x8 v; unsigned u[4]; } tmp;
                tmp.u[0] = cvtpk(lo[0], lo[1]);
                tmp.u[1] = cvtpk(lo[2], lo[3]);
                tmp.u[2] = cvtpk(hi[0], hi[1]);
                tmp.u[3] = cvtpk(hi[2], hi[3]);
                af[mi] = tmp.v;
            }
#pragma unroll
            for (int ni = 0; ni < 4; ++ni) {
                const int rr = wn + ni * 16 + lr;
                const int c  = (kk * 4 + quad) ^ (rr & 7);
                bfr[ni] = *(const bf16x8*)(sB + rr * BK + (c << 3));
            }
#pragma unroll
            for (int mi = 0; mi < 4; ++mi)
#pragma unroll
                for (int ni = 0; ni < 4; ++ni)
                    acc[mi][ni] = __builtin_amdgcn_mfma_f32_16x16x32_bf16(
                        af[mi], bfr[ni], acc[mi][ni], 0, 0, 0);
        }
        __syncthreads();
    }

    // epilogue: C/D layout col=lane&15, row=quad*4+reg (R0-verified)
#pragma unroll
    for (int ni = 0; ni < 4; ++ni) {
        const int col = n0 + wn + ni * 16 + lr;
        const float bv = bias[col];
#pragma unroll
        for (int mi = 0; mi < 4; ++mi) {
            const int row = m0 + wm + mi * 16 + quad * 4;
            float* Cp = C + (size_t)row * NN + col;
#pragma unroll
            for (int r = 0; r < 4; ++r)
                Cp[(size_t)r * NN] = acc[mi][ni][r] + bv;
        }
    }
}

extern "C" void kernel_launch(void* const* d_in, const int* in_sizes, int n_in,
                              void* d_out, int out_size, void* d_ws, size_t ws_size,
                              hipStream_t stream) {
    const float* x    = (const float*)d_in[0];
    // d_in[1] = W_gate, d_in[2] = b_gate: unused (softmax row-sum == 1)
    const float* Wexp = (const float*)d_in[3];
    const float* bexp = (const float*)d_in[4];
    float* out = (float*)d_out;

    u16*   Ws = (u16*)d_ws;                        // 1 MB
    float* bs = (float*)((char*)d_ws + 1048576);   // 8 KB

    prep_kernel<<<512, 256, 0, stream>>>(Wexp, bexp, Ws, bs);
    dim3 grid(NN / 128, MB / 128);  // (16, 256) — n fastest
    gemm_kernel<<<grid, 256, 0, stream>>>(x, Ws, bs, out);
}

// Round 5
// 341.441 us; speedup vs baseline: 1.0783x; 1.0456x over previous
//
#include <hip/hip_runtime.h>

// NestedMoEModel: B=32768, D=256, H=256, G=8, E=8.
// softmax row-sum == 1 => gate branch drops; sum_e is linear =>
// single GEMM  out[32768,2048] = x @ (sum_e W_exp)^T + sum_e b_exp.
// R7: byte-exact R0 GEMM core (single-buffered glds, __syncthreads, 3
// blocks/CU — every structural variant R1-R4 regressed). Only two zero-cost
// changes: (1) swapped-operand MFMA so acc reg-index runs along n ->
// f32x4 C-stores (R2-verified numerics, 4x fewer store issue slots),
// (2) XCD-chunked bijective block swizzle (each XCD owns 32 m-panels x all
// 16 n-blocks -> A-panel re-reads are same-XCD L2 hits).

typedef unsigned short u16;
typedef __bf16 bf16x8 __attribute__((ext_vector_type(8)));
typedef float f32x4 __attribute__((ext_vector_type(4)));

#define MB 32768   // batch (GEMM M)
#define NN 2048    // G*H   (GEMM N)
#define KK 256     // D     (GEMM K)
#define BK 64

__device__ __forceinline__ u16 f2bf(float f) {
    unsigned u = __builtin_bit_cast(unsigned, f);
    u += 0x7FFFu + ((u >> 16) & 1u);
    return (u16)(u >> 16);
}

__device__ __forceinline__ void gld16(const void* g, void* l) {
    // async global->LDS, 16B/lane; LDS dest must be wave-uniform base + lane*16
    __builtin_amdgcn_global_load_lds((const __attribute__((address_space(1))) void*)g,
                                     (__attribute__((address_space(3))) void*)l,
                                     16, 0, 0);
}

// ---------------- prep: Wsum/bsum fold + x fp32->bf16 (R0-exact) ----------------
__global__ __launch_bounds__(256) void prep_kernel(
    const float* __restrict__ x, const float* __restrict__ Wexp,
    const float* __restrict__ bexp, u16* __restrict__ xb,
    u16* __restrict__ Ws, float* __restrict__ bs)
{
    const int blk = blockIdx.x;
    const int t = threadIdx.x;
    if (blk < 512) {
        const int tid = blk * 256 + t;        // 0..131071
        const int n = tid >> 6;               // 0..2047
        const int i = (tid & 63) << 2;        // 0..252
        const int g = n >> 8, h = n & 255;
        const float* base = Wexp + ((size_t)(g * 8) * 256 + h) * 256 + i;
        float s0 = 0.f, s1 = 0.f, s2 = 0.f, s3 = 0.f;
#pragma unroll
        for (int e = 0; e < 8; ++e) {
            const float4 v = *(const float4*)(base + (size_t)e * 65536);
            s0 += v.x; s1 += v.y; s2 += v.z; s3 += v.w;
        }
        ushort4 o;
        o.x = f2bf(s0); o.y = f2bf(s1); o.z = f2bf(s2); o.w = f2bf(s3);
        *(ushort4*)(Ws + (size_t)n * KK + i) = o;
        if ((tid & 63) == 0) {
            float sb = 0.f;
#pragma unroll
            for (int e = 0; e < 8; ++e) sb += bexp[(g * 8 + e) * 256 + h];
            bs[n] = sb;
        }
    } else {
        int idx = (blk - 512) * 256 + t;      // 0..524287
        const float4* xv = (const float4*)x;
#pragma unroll
        for (int it = 0; it < 4; ++it) {
            const int j = idx + it * 524288;
            const float4 v = xv[j];
            ushort4 o;
            o.x = f2bf(v.x); o.y = f2bf(v.y); o.z = f2bf(v.z); o.w = f2bf(v.w);
            *(ushort4*)(xb + (size_t)j * 4) = o;
        }
    }
}

// ---------------- GEMM: C = A * Bt^T + bias ----------------
// 128x128 tile, BK=64, 4 waves (2x2 of 64x64), 16x16x32 bf16 MFMA.
// LDS layout: row-major 128 x 64, each row's eight 8-elem chunks permuted by
// chunk^(row&7), applied on the GLOBAL source address (glds LDS dest is
// forced to base+lane*16). Fragment reads land 2-way bank-aliased (free).
__global__ __launch_bounds__(256, 3) void gemm_kernel(
    const u16* __restrict__ A, const u16* __restrict__ Bt,
    const float* __restrict__ bias, float* __restrict__ C)
{
    __shared__ __align__(16) u16 sA[128 * BK];
    __shared__ __align__(16) u16 sB[128 * BK];

    const int t = threadIdx.x;

    // XCD-chunked bijective swizzle (4096 % 8 == 0): each XCD gets 512
    // consecutive logical tiles; logical id is n-fastest so the 16 blocks
    // sharing an A-panel are consecutive on the same XCD.
    const int bid  = blockIdx.x;
    const int rmap = (bid & 7) * 512 + (bid >> 3);
    const int n0 = (rmap & 15) << 7;
    const int m0 = (rmap >> 4) << 7;

    const int lane = t & 63;
    const int w = t >> 6;
    const int wm = (w & 1) << 6;
    const int wn = (w >> 1) << 6;
    const int lr = lane & 15;
    const int quad = lane >> 4;

    f32x4 acc[4][4] = {};

    // staging: 4 rounds per operand; slot = r*256+t -> row = slot>>3, cs = slot&7
    const int srow = t >> 3;
    const int scs  = t & 7;

    for (int k0 = 0; k0 < KK; k0 += BK) {
#pragma unroll
        for (int r = 0; r < 4; ++r) {
            const int row = srow + r * 32;
            const int gc  = ((scs ^ (row & 7)) << 3);   // swizzled element offset
            gld16(A  + (size_t)(m0 + row) * KK + k0 + gc, sA + (size_t)(r * 256 + t) * 8);
            gld16(Bt + (size_t)(n0 + row) * KK + k0 + gc, sB + (size_t)(r * 256 + t) * 8);
        }
        __syncthreads();

#pragma unroll
        for (int kk = 0; kk < 2; ++kk) {
            bf16x8 af[4], bf[4];
#pragma unroll
            for (int mi = 0; mi < 4; ++mi) {
                const int rr = wm + mi * 16 + lr;
                const int c  = (kk * 4 + quad) ^ (rr & 7);
                af[mi] = *(const bf16x8*)(sA + rr * BK + (c << 3));
            }
#pragma unroll
            for (int ni = 0; ni < 4; ++ni) {
                const int rr = wn + ni * 16 + lr;
                const int c  = (kk * 4 + quad) ^ (rr & 7);
                bf[ni] = *(const bf16x8*)(sB + rr * BK + (c << 3));
            }
            // SWAPPED operands (R2-verified): acc[mi][ni][r] =
            //   C[m0+wm+mi*16+lr][n0+wn+ni*16+quad*4+r]
#pragma unroll
            for (int mi = 0; mi < 4; ++mi)
#pragma unroll
                for (int ni = 0; ni < 4; ++ni)
                    acc[mi][ni] = __builtin_amdgcn_mfma_f32_16x16x32_bf16(
                        bf[ni], af[mi], acc[mi][ni], 0, 0, 0);
        }
        __syncthreads();
    }

    // epilogue: f32x4 stores along n (reg index r runs along n after swap)
#pragma unroll
    for (int mi = 0; mi < 4; ++mi) {
        const int row = m0 + wm + mi * 16 + lr;
        float* Cp = C + (size_t)row * NN;
#pragma unroll
        for (int ni = 0; ni < 4; ++ni) {
            const int col = n0 + wn + ni * 16 + quad * 4;
            const f32x4 bv = *(const f32x4*)(bias + col);
            f32x4 v = acc[mi][ni] + bv;
            *(f32x4*)(Cp + col) = v;
        }
    }
}

extern "C" void kernel_launch(void* const* d_in, const int* in_sizes, int n_in,
                              void* d_out, int out_size, void* d_ws, size_t ws_size,
                              hipStream_t stream) {
    const float* x    = (const float*)d_in[0];
    // d_in[1] = W_gate, d_in[2] = b_gate: unused (softmax row-sum == 1)
    const float* Wexp = (const float*)d_in[3];
    const float* bexp = (const float*)d_in[4];
    float* out = (float*)d_out;

    u16*   xb = (u16*)d_ws;                                         // 16 MB
    u16*   Ws = (u16*)((char*)d_ws + (size_t)16777216);             // 1 MB
    float* bs = (float*)((char*)d_ws + (size_t)16777216 + 1048576); // 8 KB

    prep_kernel<<<2560, 256, 0, stream>>>(x, Wexp, bexp, xb, Ws, bs);
    gemm_kernel<<<4096, 256, 0, stream>>>(xb, Ws, bs, out);
}